// Round 16
// baseline (82.110 us; speedup 1.0000x reference)
//
#include <hip/hip_runtime.h>

// FlowLenia single step — MFMA implicit-GEMM convolution (f16), fused flow+RT.
// A:[4,1,256,256,3] f32, Kn:[256,256,12] f32, m/s/h:[12], c0/c1 = arange(12)%3.
// out nA:[4,1,256,256,3] f32.
//
// Conv: 32x16 output tiles (1536 blocks), 512 thr = 8 waves = 8 K-eighths,
// each wave does both octets of the tile (1 B-load -> 2 MFMAs). LDS 36.5 KB
// -> 4 blocks/CU = 32 waves/CU (HW max). Cross-eighth LDS reduction.

typedef _Float16 f16;
typedef __attribute__((ext_vector_type(8))) _Float16 half8;
typedef __attribute__((ext_vector_type(16))) float f32x16;

#define RMAX 44
#define NROWS 89                  // 2*RMAX+1
#define NDMAX 8
#define NFRAG (3*NROWS*NDMAX)     // real fragments; slot NFRAG = zeros
#define NBPK ((NFRAG + 4) / 4)    // bpack blocks (4 frags / 256-thr block)
#define ST 152                    // LDS row stride (f16), 19 half8 chunks
#define TROWS 120                 // 32 + 2*RMAX
#define SCHED_STRIDE 1024
#define KTHR 1e-7f

// ---------------- kernel 1: per-(c,di) dj bounds + per-row radius ----------------
__global__ __launch_bounds__(128) void lenia_meta(const float* __restrict__ Kn,
                                                  int2* __restrict__ meta,
                                                  int* __restrict__ rowr) {
    int blk = blockIdx.x;                 // 3*NROWS
    int c = blk / NROWS, ri = blk - c * NROWS;
    int di = ri - RMAX;
    int t = threadIdx.x;
    int dj = t - RMAX;
    int act = 0;
    if (t < NROWS) {
        size_t base = (size_t)(((di + 128) << 8) | (dj + 128)) * 12 + c;
        float k0 = Kn[base], k1 = Kn[base + 3], k2 = Kn[base + 6], k3 = Kn[base + 9];
        act = (fmaxf(fmaxf(k0, k1), fmaxf(k2, k3)) > KTHR) ? 1 : 0;
    }
    __shared__ int smn[128], smx[128];
    smn[t] = act ? dj : 1000;
    smx[t] = act ? dj : -1000;
    __syncthreads();
    for (int s = 64; s > 0; s >>= 1) {
        if (t < s) { smn[t] = min(smn[t], smn[t + s]); smx[t] = max(smx[t], smx[t + s]); }
        __syncthreads();
    }
    if (t == 0) {
        int jmn = smn[0], jmx = smx[0];
        if (jmx < jmn) { meta[blk] = make_int2(1, 0); rowr[blk] = 0; }
        else {
            meta[blk] = make_int2(jmn, jmx);
            rowr[blk] = max(abs(di), max(abs(jmn), abs(jmx)));
        }
    }
}

// ------------- kernel 2: chunk geometry + flat schedule (w/ LDS offsets) + radii -------------
__global__ __launch_bounds__(128) void lenia_sched(const int2* __restrict__ meta,
                                                   const int* __restrict__ rowr,
                                                   int2* __restrict__ meta2,
                                                   unsigned int* __restrict__ sched,
                                                   int* __restrict__ nsched,
                                                   int* __restrict__ radii) {
    int c = blockIdx.x;                   // 3 blocks
    int t = threadIdx.x;
    __shared__ int pre[NROWS], nds[NROWS], rmx[128];
    int nd = 0, d0 = 0;
    if (t < NROWS) {
        int2 bm = meta[c * NROWS + t];
        if (bm.y >= bm.x) {
            d0 = ((bm.x - 7) >> 3) << 3;          // delta0 <= jmn-7, mult of 8
            nd = ((bm.y + 7 - d0) >> 4) + 1;      // cover dj' = jmx for sy up to 7
        }
        meta2[c * NROWS + t] = make_int2(d0, nd);
        nds[t] = nd;
    }
    rmx[t] = (t < NROWS) ? rowr[c * NROWS + t] : 0;
    __syncthreads();
    for (int s = 64; s > 0; s >>= 1) {
        if (t < s) rmx[t] = max(rmx[t], rmx[t + s]);
        __syncthreads();
    }
    __shared__ int tot;
    if (t == 0) {
        radii[c] = rmx[0];
        int acc = 0;
        for (int i = 0; i < NROWS; ++i) { pre[i] = acc; acc += nds[i]; }
        tot = acc;
    }
    __syncthreads();
    if (t < NROWS && nd > 0) {
        int base = pre[t];
        for (int i = 0; i < nd; ++i) {
            int delta = d0 + 16 * i;
            unsigned int off = (unsigned int)(t * ST + delta + 128);   // 14 bits
            sched[c * SCHED_STRIDE + base + i] =
                (unsigned int)((c * NROWS + t) * NDMAX + i) | (off << 12);
        }
    }
    if (t == 0) {
        int ns = (tot + 63) & ~63;        // mult of 64 -> eighths are mult of 8
        unsigned int padoff = (unsigned int)(RMAX * ST + 128);
        for (int i = tot; i < ns + 48; ++i)       // pads: zero frag, valid lds addr
            sched[c * SCHED_STRIDE + i] = (unsigned int)NFRAG | (padoff << 12);
        nsched[c] = ns;
    }
}

// ------- kernel 3: FUSED bpack-from-Kn (blocks < NBPK) + A-transpose (rest) -------
__global__ __launch_bounds__(256) void lenia_prep2(const float* __restrict__ Kn,
                                                   const float* __restrict__ A,
                                                   const int2* __restrict__ meta2,
                                                   uint4* __restrict__ bpack,
                                                   f16* __restrict__ Atr) {
    int blk = blockIdx.x;
    if (blk < NBPK) {                     // ---- bpack part ----
        int fi = blk * 4 + (threadIdx.x >> 6);
        int l = threadIdx.x & 63;
        if (fi > NFRAG) return;
        union { f16 h[8]; uint4 u; } pk;
        if (fi == NFRAG) {
            pk.u = make_uint4(0, 0, 0, 0);
            bpack[(size_t)fi * 64 + l] = pk.u;
            return;
        }
        int c = fi / (NROWS * NDMAX);
        int rem = fi - c * (NROWS * NDMAX);
        int ri = rem >> 3, didx = rem & 7;
        int di = ri - RMAX;
        int delta = meta2[c * NROWS + ri].x + 16 * didx;
        int q = (l & 31) >> 3, sy = l & 7, g = l >> 5;
        int dj0 = delta + 8 * g - sy;     // in [-63, 71]: row-local, in-bounds
        const float* src = Kn + (size_t)(((di + 128) << 8) + (dj0 + 128)) * 12 + c + 3 * q;
        #pragma unroll
        for (int j = 0; j < 8; ++j) pk.h[j] = (f16)src[j * 12];
        bpack[(size_t)fi * 64 + l] = pk.u;
    } else {                              // ---- A-transpose part ----
        int px = (blk - NBPK) * 256 + threadIdx.x;   // 0..262143
        int b = px >> 16, rem = px & 65535;
        const float* ap = A + (size_t)px * 3;
        Atr[(size_t)(b * 3 + 0) * 65536 + rem] = (f16)ap[0];
        Atr[(size_t)(b * 3 + 1) * 65536 + rem] = (f16)ap[1];
        Atr[(size_t)(b * 3 + 2) * 65536 + rem] = (f16)ap[2];
    }
}

// ---------------- kernel 4: MFMA conv + growth -> Uc (f16, in ws) ----------------
// 32x16 tile per block; 512 thr = 8 waves; wave e runs schedule eighth e for
// both octets (1 B-load -> 2 MFMAs). 3-round cross-eighth LDS reduce; growth
// + store on wave 0.
__global__ __launch_bounds__(512, 8) void lenia_conv(
        const f16* __restrict__ Atr, const uint4* __restrict__ bpack,
        const unsigned int* __restrict__ sched, const int* __restrict__ nsched,
        const int* __restrict__ radii,
        const float* __restrict__ mp, const float* __restrict__ sp,
        const float* __restrict__ hp, f16* __restrict__ Uc) {
    extern __shared__ f16 smh[];

    const int tid = threadIdx.x;
    const int bc = blockIdx.y;
    const int b = bc / 3, c = bc - b * 3;
    const int t = blockIdx.x;             // 128 tiles: 8 x-tiles x 16 y-tiles
    const int x0 = (t >> 4) << 5;
    const int y0 = (t & 15) << 4;

    const int R = __builtin_amdgcn_readfirstlane(min(max(radii[c], 1), RMAX));
    const int R8 = (R + 7) & ~7;
    const int colbase = y0 - R8 - 16;     // mult of 8
    const int rows = 32 + 2 * R;
    const f16* Ap = Atr + (size_t)(b * 3 + c) * 65536;

    {   // staging: half8 (16B) chunks; 19 chunks/row; 512 threads
        int nchunk = rows * 19;
        int tr = tid / 19, rem = tid - tr * 19;
        for (int ci = tid; ci < nchunk; ci += 512) {
            int gi = (x0 - R + tr) & 255;
            int gj = (colbase + rem * 8) & 255;   // mult of 8 -> never crosses wrap
            *(half8*)(smh + tr * ST + rem * 8) = *(const half8*)(Ap + (gi << 8) + gj);
            tr += 26; rem += 18;                  // +512 chunks = 26*19 + 18
            if (rem >= 19) { rem -= 19; ++tr; }
        }
    }
    __syncthreads();

    const int lane = tid & 63, e = tid >> 6;      // 8 waves, eighth e
    const int m = lane & 31, g = lane >> 5;
    const int abase = (m + R - RMAX) * ST + R8 + 16 + 8 * g - 128;

    const int ns = __builtin_amdgcn_readfirstlane(nsched[c]);   // mult of 64
    const int nsE = ns >> 3;                                    // mult of 8
    const unsigned int* sW = sched + c * SCHED_STRIDE + e * nsE;

    f32x16 accA, accB;                    // octet 0 / octet 1 chains
    #pragma unroll
    for (int r = 0; r < 16; ++r) { accA[r] = 0.f; accB[r] = 0.f; }

    int eq[8];
    uint4 bq[8];
    #pragma unroll
    for (int j = 0; j < 8; ++j) {
        int ev = __builtin_amdgcn_readfirstlane((int)sW[j]);
        eq[j] = ev;
        bq[j] = bpack[(size_t)(ev & 4095) * 64 + lane];
    }

    for (int it = 0; it < nsE; it += 8) {
        #pragma unroll
        for (int j = 0; j < 8; ++j) {
            const int off = abase + (eq[j] >> 12);
            half8 a0 = *(const half8*)(smh + off);
            half8 a1 = *(const half8*)(smh + off + 8);
            union { uint4 u; half8 h; } bb; bb.u = bq[j];
            accA = __builtin_amdgcn_mfma_f32_32x32x16_f16(a0, bb.h, accA, 0, 0, 0);
            accB = __builtin_amdgcn_mfma_f32_32x32x16_f16(a1, bb.h, accB, 0, 0, 0);
            int ne = __builtin_amdgcn_readfirstlane((int)sW[it + 8 + j]);
            eq[j] = ne;
            bq[j] = bpack[(size_t)(ne & 4095) * 64 + lane];
        }
    }

    // ---- 3-round cross-eighth reduction in LDS (A tile dead); stride 33 ----
    float* red = (float*)smh;             // max 4 groups x 64 lanes x 33 f32 = 33.8 KB
    __syncthreads();
    if (e >= 4) {
        float* dst = red + ((size_t)((e - 4) * 64 + lane)) * 33;
        #pragma unroll
        for (int r = 0; r < 16; ++r) { dst[r] = accA[r]; dst[16 + r] = accB[r]; }
    }
    __syncthreads();
    if (e < 4) {
        const float* src = red + ((size_t)(e * 64 + lane)) * 33;
        #pragma unroll
        for (int r = 0; r < 16; ++r) { accA[r] += src[r]; accB[r] += src[16 + r]; }
    }
    __syncthreads();
    if (e == 2 || e == 3) {
        float* dst = red + ((size_t)((e - 2) * 64 + lane)) * 33;
        #pragma unroll
        for (int r = 0; r < 16; ++r) { dst[r] = accA[r]; dst[16 + r] = accB[r]; }
    }
    __syncthreads();
    if (e < 2) {
        const float* src = red + ((size_t)(e * 64 + lane)) * 33;
        #pragma unroll
        for (int r = 0; r < 16; ++r) { accA[r] += src[r]; accB[r] += src[16 + r]; }
    }
    __syncthreads();
    if (e == 1) {
        float* dst = red + (size_t)lane * 33;
        #pragma unroll
        for (int r = 0; r < 16; ++r) { dst[r] = accA[r]; dst[16 + r] = accB[r]; }
    }
    __syncthreads();
    if (e == 0) {
        const float* src = red + (size_t)lane * 33;
        #pragma unroll
        for (int r = 0; r < 16; ++r) { accA[r] += src[r]; accB[r] += src[16 + r]; }

        // growth + sum over q (lanes l, l^8, l^16) -> Uc (f16), octets 0,1
        const int q = (lane & 31) >> 3, sy = lane & 7;
        const float mq = mp[c + 3 * q];
        const float sq = sp[c + 3 * q];
        const float hq = hp[c + 3 * q];
        const float i2s = 1.f / (2.f * sq * sq);
        #pragma unroll
        for (int oo = 0; oo < 2; ++oo) {
            const f32x16& acc = oo ? accB : accA;
            const int col = y0 + 8 * oo + sy;
            #pragma unroll
            for (int r = 0; r < 16; ++r) {
                float d = acc[r] - mq;
                float gg = (2.f * expf(-d * d * i2s) - 1.f) * hq;
                gg += __shfl_xor(gg, 8);
                gg += __shfl_xor(gg, 16);
                if ((lane & 24) == 0) {
                    int row = (r & 3) + ((r >> 2) << 3) + (g << 2);
                    Uc[((size_t)(b << 16) + ((x0 + row) << 8) + col) * 3 + c] = (f16)gg;
                }
            }
        }
    }
}

// ------- kernel 5: fused sobel+flow+mus + RT, PER-CHANNEL blocks (grid 64x12) -------
#define FTW 44
#define FSW 45
#define PLH (FSW * FTW)           // 1980 elems per plane
__global__ __launch_bounds__(256) void lenia_flowrt(
        const f16* __restrict__ Atr, const f16* __restrict__ Uc,
        float* __restrict__ out) {
    extern __shared__ char fraw[];
    f16*    ucp = (f16*)fraw;                    // [PLH]       uc, this channel
    f16*    atp = (f16*)(fraw + PLH * 2);        // [3][PLH]    A, all channels
    float2* muq = (float2*)(fraw + 8 * PLH);     // [PLH]       (dx, dy), this channel

    int bc = blockIdx.y;                         // 12: b*3+c
    int b = bc / 3, c = bc - b * 3;
    int t = blockIdx.x;                          // 64 tiles of 32x32
    int x0 = (t >> 3) << 5, y0 = (t & 7) << 5;
    const f16* A0 = Atr + (size_t)(b * 3) * 65536;
    const f16* Ub = Uc + ((size_t)b << 16) * 3;

    for (int idx = threadIdx.x; idx < FTW * FTW; idx += 256) {
        int si = idx / FTW, sj = idx - si * FTW;
        int gi = (x0 - 6 + si) & 255, gj = (y0 - 6 + sj) & 255;
        int pix = (gi << 8) + gj;
        int o = si * FSW + sj;
        ucp[o] = Ub[(size_t)pix * 3 + c];
        atp[o] = A0[pix];
        atp[PLH + o] = A0[65536 + pix];
        atp[2 * PLH + o] = A0[131072 + pix];
    }
    __syncthreads();

    // mus phase: 42x42 cells (this channel only)
    for (int idx = threadIdx.x; idx < 42 * 42; idx += 256) {
        int ci = idx / 42, cj = idx - ci * 42;
        int si = ci + 1, sj = cj + 1;
        int o = si * FSW + sj;
        int vx = x0 - 6 + si, vy = y0 - 6 + sj;
        float sx = (vx < 0 || vx > 255) ? 1e7f : 0.f;
        float syv = (vy < 0 || vy > 255) ? 1e7f : 0.f;

        float as[3][3];
        #pragma unroll
        for (int i = 0; i < 3; ++i)
            #pragma unroll
            for (int j = 0; j < 3; ++j) {
                int oo = o + (i - 1) * FSW + (j - 1);
                as[i][j] = (float)atp[oo] + (float)atp[PLH + oo] + (float)atp[2 * PLH + oo];
            }
        float gxA = ((as[2][0] + 2.f * as[2][1] + as[2][2])
                   - (as[0][0] + 2.f * as[0][1] + as[0][2])) * 0.125f;
        float gyA = ((as[0][2] + 2.f * as[1][2] + as[2][2])
                   - (as[0][0] + 2.f * as[1][0] + as[2][0])) * 0.125f;

        float u00 = ucp[o - FSW - 1], u01 = ucp[o - FSW], u02 = ucp[o - FSW + 1];
        float u10 = ucp[o - 1],                          u12 = ucp[o + 1];
        float u20 = ucp[o + FSW - 1], u21 = ucp[o + FSW], u22 = ucp[o + FSW + 1];
        float gx = ((u20 + 2.f * u21 + u22) - (u00 + 2.f * u01 + u02)) * 0.125f;
        float gy = ((u02 + 2.f * u12 + u22) - (u00 + 2.f * u10 + u20)) * 0.125f;
        float a = (float)atp[c * PLH + o];
        float alpha = fminf(a * a, 1.f);
        float Fx = gx * (1.f - alpha) - gxA * alpha;
        float Fy = gy * (1.f - alpha) - gyA * alpha;
        float dx = fminf(fmaxf(0.2f * Fx, -4.35f), 4.35f) + sx;
        float dy = fminf(fmaxf(0.2f * Fy, -4.35f), 4.35f) + syv;
        muq[o] = make_float2(dx, dy);
    }
    __syncthreads();

    // gather: thread = (x col tx, y quad tyg), this channel
    int tx = threadIdx.x & 31, tyg = threadIdx.x >> 5;
    int ty0 = tyg << 2;
    float a0 = 0.f, a1 = 0.f, a2 = 0.f, a3 = 0.f;
    const f16* ac = atp + c * PLH;

    for (int dxs = 0; dxs < 11; ++dxs) {
        float fdx = (float)(5 - dxs);
        int rowb = (tx + 1 + dxs) * FSW + (ty0 + 1);
        #pragma unroll
        for (int sjj = 0; sjj < 14; ++sjj) {
            float fdy = (float)(5 - sjj);
            float2 mu = muq[rowb + sjj];
            float av = (float)ac[rowb + sjj];
            float wx = fminf(fmaxf(1.15f - fabsf(fdx - mu.x), 0.f), 1.f);
            float awx = av * wx;
            float e0 = fdy - mu.y;
            a0 = fmaf(awx, fminf(fmaxf(1.15f - fabsf(e0), 0.f), 1.f), a0);
            a1 = fmaf(awx, fminf(fmaxf(1.15f - fabsf(e0 + 1.f), 0.f), 1.f), a1);
            a2 = fmaf(awx, fminf(fmaxf(1.15f - fabsf(e0 + 2.f), 0.f), 1.f), a2);
            a3 = fmaf(awx, fminf(fmaxf(1.15f - fabsf(e0 + 3.f), 0.f), 1.f), a3);
        }
    }
    const float inv = 1.0f / 1.69f;   // 1/(4*sigma^2)
    size_t ob = ((size_t)(b << 16) + ((x0 + tx) << 8) + (y0 + ty0)) * 3 + c;
    out[ob]     = a0 * inv;
    out[ob + 3] = a1 * inv;
    out[ob + 6] = a2 * inv;
    out[ob + 9] = a3 * inv;
}

extern "C" void kernel_launch(void* const* d_in, const int* in_sizes, int n_in,
                              void* d_out, int out_size, void* d_ws, size_t ws_size,
                              hipStream_t stream) {
    const float* A  = (const float*)d_in[0];
    const float* Kn = (const float*)d_in[1];
    const float* m  = (const float*)d_in[2];
    const float* s  = (const float*)d_in[3];
    const float* h  = (const float*)d_in[4];

    char* ws = (char*)d_ws;
    int*          radii = (int*)ws;                        // 16 B
    int*          nschd = (int*)(ws + 16);
    int*          rowr  = (int*)(ws + 64);                 // 267*4
    int2*         meta  = (int2*)(ws + 2048);              // 267*8
    int2*         meta2 = (int2*)(ws + 8192);              // 267*8
    unsigned int* sched = (unsigned int*)(ws + 16384);     // 12 KB
    f16*          Atr   = (f16*)(ws + 32768);              // 1.57 MB
    uint4*        bpack = (uint4*)(ws + 1605632);          // 2.19 MB
    f16*          Uc    = (f16*)(ws + 3793920);            // 1.57 MB -> ends 5.37 MB

    lenia_meta<<<3 * NROWS, 128, 0, stream>>>(Kn, meta, rowr);
    lenia_sched<<<3, 128, 0, stream>>>(meta, rowr, meta2, sched, nschd, radii);
    lenia_prep2<<<NBPK + 1024, 256, 0, stream>>>(Kn, A, meta2, bpack, Atr);
    lenia_conv<<<dim3(128, 12), 512, TROWS * ST * sizeof(f16), stream>>>(
        Atr, bpack, sched, nschd, radii, m, s, h, Uc);
    lenia_flowrt<<<dim3(64, 12), 256, 8 * PLH + PLH * 8, stream>>>(
        Atr, Uc, (float*)d_out);
}

// Round 17
// 69.259 us; speedup vs baseline: 1.1855x; 1.1855x over previous
//
#include <hip/hip_runtime.h>

// FlowLenia single step — MFMA implicit-GEMM convolution (f16), fused flow+RT.
// A:[4,1,256,256,3] f32, Kn:[256,256,12] f32, m/s/h:[12], c0/c1 = arange(12)%3.
// out nA:[4,1,256,256,3] f32.
//
// Conv (r15 structure): 512 thr = 8 waves = 4 K-quarters x 2 octet-pairs;
// wave (qr,p) runs quarter qr for octets {2p,2p+1} (1 B-load -> 2 MFMAs);
// cross-quarter LDS reduction. NEW: XCD-aware bijective block reorder so each
// XCD's L2 sees a c-major contiguous range (bpack stays L2-hot).

typedef _Float16 f16;
typedef __attribute__((ext_vector_type(8))) _Float16 half8;
typedef __attribute__((ext_vector_type(16))) float f32x16;

#define RMAX 44
#define NROWS 89                  // 2*RMAX+1
#define NDMAX 8
#define NFRAG (3*NROWS*NDMAX)     // real fragments; slot NFRAG = zeros
#define NBPK ((NFRAG + 4) / 4)    // bpack blocks (4 frags / 256-thr block)
#define ST 168                    // LDS row stride (f16), 21 half8 chunks
#define TROWS 120                 // 32 + 2*RMAX
#define SCHED_STRIDE 1024
#define KTHR 1e-7f

// ---------------- kernel 1: per-(c,di) dj bounds + per-row radius ----------------
__global__ __launch_bounds__(128) void lenia_meta(const float* __restrict__ Kn,
                                                  int2* __restrict__ meta,
                                                  int* __restrict__ rowr) {
    int blk = blockIdx.x;                 // 3*NROWS
    int c = blk / NROWS, ri = blk - c * NROWS;
    int di = ri - RMAX;
    int t = threadIdx.x;
    int dj = t - RMAX;
    int act = 0;
    if (t < NROWS) {
        size_t base = (size_t)(((di + 128) << 8) | (dj + 128)) * 12 + c;
        float k0 = Kn[base], k1 = Kn[base + 3], k2 = Kn[base + 6], k3 = Kn[base + 9];
        act = (fmaxf(fmaxf(k0, k1), fmaxf(k2, k3)) > KTHR) ? 1 : 0;
    }
    __shared__ int smn[128], smx[128];
    smn[t] = act ? dj : 1000;
    smx[t] = act ? dj : -1000;
    __syncthreads();
    for (int s = 64; s > 0; s >>= 1) {
        if (t < s) { smn[t] = min(smn[t], smn[t + s]); smx[t] = max(smx[t], smx[t + s]); }
        __syncthreads();
    }
    if (t == 0) {
        int jmn = smn[0], jmx = smx[0];
        if (jmx < jmn) { meta[blk] = make_int2(1, 0); rowr[blk] = 0; }
        else {
            meta[blk] = make_int2(jmn, jmx);
            rowr[blk] = max(abs(di), max(abs(jmn), abs(jmx)));
        }
    }
}

// ------------- kernel 2: chunk geometry + flat schedule (w/ LDS offsets) + radii -------------
__global__ __launch_bounds__(128) void lenia_sched(const int2* __restrict__ meta,
                                                   const int* __restrict__ rowr,
                                                   int2* __restrict__ meta2,
                                                   unsigned int* __restrict__ sched,
                                                   int* __restrict__ nsched,
                                                   int* __restrict__ radii) {
    int c = blockIdx.x;                   // 3 blocks
    int t = threadIdx.x;
    __shared__ int pre[NROWS], nds[NROWS], rmx[128];
    int nd = 0, d0 = 0;
    if (t < NROWS) {
        int2 bm = meta[c * NROWS + t];
        if (bm.y >= bm.x) {
            d0 = ((bm.x - 7) >> 3) << 3;          // delta0 <= jmn-7, mult of 8
            nd = ((bm.y + 7 - d0) >> 4) + 1;      // cover dj' = jmx for sy up to 7
        }
        meta2[c * NROWS + t] = make_int2(d0, nd);
        nds[t] = nd;
    }
    rmx[t] = (t < NROWS) ? rowr[c * NROWS + t] : 0;
    __syncthreads();
    for (int s = 64; s > 0; s >>= 1) {
        if (t < s) rmx[t] = max(rmx[t], rmx[t + s]);
        __syncthreads();
    }
    __shared__ int tot;
    if (t == 0) {
        radii[c] = rmx[0];
        int acc = 0;
        for (int i = 0; i < NROWS; ++i) { pre[i] = acc; acc += nds[i]; }
        tot = acc;
    }
    __syncthreads();
    if (t < NROWS && nd > 0) {
        int base = pre[t];
        for (int i = 0; i < nd; ++i) {
            int delta = d0 + 16 * i;
            unsigned int off = (unsigned int)(t * ST + delta + 128);   // 14 bits
            sched[c * SCHED_STRIDE + base + i] =
                (unsigned int)((c * NROWS + t) * NDMAX + i) | (off << 12);
        }
    }
    if (t == 0) {
        int ns = (tot + 31) & ~31;        // mult of 32 -> quarters are mult of 8
        unsigned int padoff = (unsigned int)(RMAX * ST + 128);
        for (int i = tot; i < ns + 48; ++i)       // pads: zero frag, valid lds addr
            sched[c * SCHED_STRIDE + i] = (unsigned int)NFRAG | (padoff << 12);
        nsched[c] = ns;
    }
}

// ------- kernel 3: FUSED bpack-from-Kn (blocks < NBPK) + A-transpose (rest) -------
__global__ __launch_bounds__(256) void lenia_prep2(const float* __restrict__ Kn,
                                                   const float* __restrict__ A,
                                                   const int2* __restrict__ meta2,
                                                   uint4* __restrict__ bpack,
                                                   f16* __restrict__ Atr) {
    int blk = blockIdx.x;
    if (blk < NBPK) {                     // ---- bpack part ----
        int fi = blk * 4 + (threadIdx.x >> 6);
        int l = threadIdx.x & 63;
        if (fi > NFRAG) return;
        union { f16 h[8]; uint4 u; } pk;
        if (fi == NFRAG) {
            pk.u = make_uint4(0, 0, 0, 0);
            bpack[(size_t)fi * 64 + l] = pk.u;
            return;
        }
        int c = fi / (NROWS * NDMAX);
        int rem = fi - c * (NROWS * NDMAX);
        int ri = rem >> 3, didx = rem & 7;
        int di = ri - RMAX;
        int delta = meta2[c * NROWS + ri].x + 16 * didx;
        int q = (l & 31) >> 3, sy = l & 7, g = l >> 5;
        int dj0 = delta + 8 * g - sy;     // in [-63, 71]: row-local, in-bounds
        const float* src = Kn + (size_t)(((di + 128) << 8) + (dj0 + 128)) * 12 + c + 3 * q;
        #pragma unroll
        for (int j = 0; j < 8; ++j) pk.h[j] = (f16)src[j * 12];
        bpack[(size_t)fi * 64 + l] = pk.u;
    } else {                              // ---- A-transpose part ----
        int px = (blk - NBPK) * 256 + threadIdx.x;   // 0..262143
        int b = px >> 16, rem = px & 65535;
        const float* ap = A + (size_t)px * 3;
        Atr[(size_t)(b * 3 + 0) * 65536 + rem] = (f16)ap[0];
        Atr[(size_t)(b * 3 + 1) * 65536 + rem] = (f16)ap[1];
        Atr[(size_t)(b * 3 + 2) * 65536 + rem] = (f16)ap[2];
    }
}

// ---------------- kernel 4: MFMA conv + growth -> Uc (f16, in ws) ----------------
// 512 thr = 8 waves; wave (qr = wid>>1, p = wid&1): schedule quarter qr,
// octets {2p, 2p+1}. 8-deep in-place B ring, scalar schedule. Cross-quarter
// LDS reduce (2 pairwise rounds), growth+store on qr==0 waves.
// Block reorder: virt = (bid&7)*96 + (bid>>3), decoded c-major -> each XCD
// (assuming xcd = bid%8) sees a contiguous c-major range (bpack L2-hot).
__global__ __launch_bounds__(512, 6) void lenia_conv(
        const f16* __restrict__ Atr, const uint4* __restrict__ bpack,
        const unsigned int* __restrict__ sched, const int* __restrict__ nsched,
        const int* __restrict__ radii,
        const float* __restrict__ mp, const float* __restrict__ sp,
        const float* __restrict__ hp, f16* __restrict__ Uc) {
    extern __shared__ f16 smh[];

    const int tid = threadIdx.x;
    const int bid = blockIdx.y * 64 + blockIdx.x;     // 0..767
    const int virt = (bid & 7) * 96 + (bid >> 3);     // bijective on [0,768)
    const int c = virt >> 8;                          // c-major decode
    const int rem0 = virt & 255;
    const int b = rem0 >> 6;
    const int t = rem0 & 63;
    const int x0 = (t >> 3) << 5;
    const int y0 = (t & 7) << 5;

    const int R = __builtin_amdgcn_readfirstlane(min(max(radii[c], 1), RMAX));
    const int R8 = (R + 7) & ~7;
    const int colbase = y0 - R8 - 16;     // mult of 8
    const int rows = 32 + 2 * R;
    const f16* Ap = Atr + (size_t)(b * 3 + c) * 65536;

    {   // staging: half8 (16B) chunks; 21 chunks/row; 512 threads
        int nchunk = rows * 21;
        int tr = tid / 21, rem = tid - tr * 21;
        for (int ci = tid; ci < nchunk; ci += 512) {
            int gi = (x0 - R + tr) & 255;
            int gj = (colbase + rem * 8) & 255;   // mult of 8 -> never crosses wrap
            *(half8*)(smh + tr * ST + rem * 8) = *(const half8*)(Ap + (gi << 8) + gj);
            tr += 24; rem += 8;                   // +512 chunks = 24*21 + 8
            if (rem >= 21) { rem -= 21; ++tr; }
        }
    }
    __syncthreads();

    const int lane = tid & 63, wid = tid >> 6;    // 8 waves
    const int p = wid & 1, qr = wid >> 1;         // octet-pair p, quarter qr
    const int m = lane & 31, g = lane >> 5;
    // octet 2p base (octet 2p+1 = +8), incl. the -128 bias of sched offsets
    const int abase = (m + R - RMAX) * ST + 16 * p + R8 + 16 + 8 * g - 128;

    const int ns = __builtin_amdgcn_readfirstlane(nsched[c]);   // mult of 32
    const int nsQ = ns >> 2;                                    // mult of 8
    const unsigned int* sW = sched + c * SCHED_STRIDE + qr * nsQ;

    f32x16 accA, accB;                    // octet 2p / octet 2p+1 chains
    #pragma unroll
    for (int r = 0; r < 16; ++r) { accA[r] = 0.f; accB[r] = 0.f; }

    int eq[8];
    uint4 bq[8];
    #pragma unroll
    for (int j = 0; j < 8; ++j) {
        int e = __builtin_amdgcn_readfirstlane((int)sW[j]);
        eq[j] = e;
        bq[j] = bpack[(size_t)(e & 4095) * 64 + lane];
    }

    for (int it = 0; it < nsQ; it += 8) {
        #pragma unroll
        for (int j = 0; j < 8; ++j) {
            const int off = abase + (eq[j] >> 12);
            half8 a0 = *(const half8*)(smh + off);
            half8 a1 = *(const half8*)(smh + off + 8);
            union { uint4 u; half8 h; } bb; bb.u = bq[j];
            accA = __builtin_amdgcn_mfma_f32_32x32x16_f16(a0, bb.h, accA, 0, 0, 0);
            accB = __builtin_amdgcn_mfma_f32_32x32x16_f16(a1, bb.h, accB, 0, 0, 0);
            int ne = __builtin_amdgcn_readfirstlane((int)sW[it + 8 + j]);
            eq[j] = ne;
            bq[j] = bpack[(size_t)(ne & 4095) * 64 + lane];
        }
    }

    // ---- cross-quarter reduction in LDS (A tile dead); stride 33 = conflict-free ----
    __syncthreads();
    float* red = (float*)smh;             // max 4 groups x 64 lanes x 33 f32 = 33 KB
    if (qr >= 2) {                        // quarters 2,3 write
        float* dst = red + ((size_t)(((p << 1) + (qr - 2)) * 64 + lane)) * 33;
        #pragma unroll
        for (int r = 0; r < 16; ++r) { dst[r] = accA[r]; dst[16 + r] = accB[r]; }
    }
    __syncthreads();
    if (qr < 2) {                         // quarters 0,1 add
        const float* src = red + ((size_t)(((p << 1) + qr) * 64 + lane)) * 33;
        #pragma unroll
        for (int r = 0; r < 16; ++r) { accA[r] += src[r]; accB[r] += src[16 + r]; }
    }
    __syncthreads();
    if (qr == 1) {                        // quarter 1 writes combined
        float* dst = red + ((size_t)(p * 64 + lane)) * 33;
        #pragma unroll
        for (int r = 0; r < 16; ++r) { dst[r] = accA[r]; dst[16 + r] = accB[r]; }
    }
    __syncthreads();
    if (qr == 0) {
        const float* src = red + ((size_t)(p * 64 + lane)) * 33;
        #pragma unroll
        for (int r = 0; r < 16; ++r) { accA[r] += src[r]; accB[r] += src[16 + r]; }

        // growth + sum over q (lanes l, l^8, l^16) -> Uc (f16), octets 2p, 2p+1
        const int q = (lane & 31) >> 3, sy = lane & 7;
        const float mq = mp[c + 3 * q];
        const float sq = sp[c + 3 * q];
        const float hq = hp[c + 3 * q];
        const float i2s = 1.f / (2.f * sq * sq);
        #pragma unroll
        for (int oo = 0; oo < 2; ++oo) {
            const f32x16& acc = oo ? accB : accA;
            const int col = y0 + 16 * p + 8 * oo + sy;
            #pragma unroll
            for (int r = 0; r < 16; ++r) {
                float d = acc[r] - mq;
                float gg = (2.f * expf(-d * d * i2s) - 1.f) * hq;
                gg += __shfl_xor(gg, 8);
                gg += __shfl_xor(gg, 16);
                if ((lane & 24) == 0) {
                    int row = (r & 3) + ((r >> 2) << 3) + (g << 2);
                    Uc[((size_t)(b << 16) + ((x0 + row) << 8) + col) * 3 + c] = (f16)gg;
                }
            }
        }
    }
}

// ------- kernel 5: fused sobel+flow+mus + RT, PER-CHANNEL blocks (grid 64x12) -------
#define FTW 44
#define FSW 45
#define PLH (FSW * FTW)           // 1980 elems per plane
__global__ __launch_bounds__(256) void lenia_flowrt(
        const f16* __restrict__ Atr, const f16* __restrict__ Uc,
        float* __restrict__ out) {
    extern __shared__ char fraw[];
    f16*    ucp = (f16*)fraw;                    // [PLH]       uc, this channel
    f16*    atp = (f16*)(fraw + PLH * 2);        // [3][PLH]    A, all channels
    float2* muq = (float2*)(fraw + 8 * PLH);     // [PLH]       (dx, dy), this channel

    int bc = blockIdx.y;                         // 12: b*3+c
    int b = bc / 3, c = bc - b * 3;
    int t = blockIdx.x;                          // 64 tiles of 32x32
    int x0 = (t >> 3) << 5, y0 = (t & 7) << 5;
    const f16* A0 = Atr + (size_t)(b * 3) * 65536;
    const f16* Ub = Uc + ((size_t)b << 16) * 3;

    for (int idx = threadIdx.x; idx < FTW * FTW; idx += 256) {
        int si = idx / FTW, sj = idx - si * FTW;
        int gi = (x0 - 6 + si) & 255, gj = (y0 - 6 + sj) & 255;
        int pix = (gi << 8) + gj;
        int o = si * FSW + sj;
        ucp[o] = Ub[(size_t)pix * 3 + c];
        atp[o] = A0[pix];
        atp[PLH + o] = A0[65536 + pix];
        atp[2 * PLH + o] = A0[131072 + pix];
    }
    __syncthreads();

    // mus phase: 42x42 cells (this channel only)
    for (int idx = threadIdx.x; idx < 42 * 42; idx += 256) {
        int ci = idx / 42, cj = idx - ci * 42;
        int si = ci + 1, sj = cj + 1;
        int o = si * FSW + sj;
        int vx = x0 - 6 + si, vy = y0 - 6 + sj;
        float sx = (vx < 0 || vx > 255) ? 1e7f : 0.f;
        float syv = (vy < 0 || vy > 255) ? 1e7f : 0.f;

        float as[3][3];
        #pragma unroll
        for (int i = 0; i < 3; ++i)
            #pragma unroll
            for (int j = 0; j < 3; ++j) {
                int oo = o + (i - 1) * FSW + (j - 1);
                as[i][j] = (float)atp[oo] + (float)atp[PLH + oo] + (float)atp[2 * PLH + oo];
            }
        float gxA = ((as[2][0] + 2.f * as[2][1] + as[2][2])
                   - (as[0][0] + 2.f * as[0][1] + as[0][2])) * 0.125f;
        float gyA = ((as[0][2] + 2.f * as[1][2] + as[2][2])
                   - (as[0][0] + 2.f * as[1][0] + as[2][0])) * 0.125f;

        float u00 = ucp[o - FSW - 1], u01 = ucp[o - FSW], u02 = ucp[o - FSW + 1];
        float u10 = ucp[o - 1],                          u12 = ucp[o + 1];
        float u20 = ucp[o + FSW - 1], u21 = ucp[o + FSW], u22 = ucp[o + FSW + 1];
        float gx = ((u20 + 2.f * u21 + u22) - (u00 + 2.f * u01 + u02)) * 0.125f;
        float gy = ((u02 + 2.f * u12 + u22) - (u00 + 2.f * u10 + u20)) * 0.125f;
        float a = (float)atp[c * PLH + o];
        float alpha = fminf(a * a, 1.f);
        float Fx = gx * (1.f - alpha) - gxA * alpha;
        float Fy = gy * (1.f - alpha) - gyA * alpha;
        float dx = fminf(fmaxf(0.2f * Fx, -4.35f), 4.35f) + sx;
        float dy = fminf(fmaxf(0.2f * Fy, -4.35f), 4.35f) + syv;
        muq[o] = make_float2(dx, dy);
    }
    __syncthreads();

    // gather: thread = (x col tx, y quad tyg), this channel
    int tx = threadIdx.x & 31, tyg = threadIdx.x >> 5;
    int ty0 = tyg << 2;
    float a0 = 0.f, a1 = 0.f, a2 = 0.f, a3 = 0.f;
    const f16* ac = atp + c * PLH;

    for (int dxs = 0; dxs < 11; ++dxs) {
        float fdx = (float)(5 - dxs);
        int rowb = (tx + 1 + dxs) * FSW + (ty0 + 1);
        #pragma unroll
        for (int sjj = 0; sjj < 14; ++sjj) {
            float fdy = (float)(5 - sjj);
            float2 mu = muq[rowb + sjj];
            float av = (float)ac[rowb + sjj];
            float wx = fminf(fmaxf(1.15f - fabsf(fdx - mu.x), 0.f), 1.f);
            float awx = av * wx;
            float e0 = fdy - mu.y;
            a0 = fmaf(awx, fminf(fmaxf(1.15f - fabsf(e0), 0.f), 1.f), a0);
            a1 = fmaf(awx, fminf(fmaxf(1.15f - fabsf(e0 + 1.f), 0.f), 1.f), a1);
            a2 = fmaf(awx, fminf(fmaxf(1.15f - fabsf(e0 + 2.f), 0.f), 1.f), a2);
            a3 = fmaf(awx, fminf(fmaxf(1.15f - fabsf(e0 + 3.f), 0.f), 1.f), a3);
        }
    }
    const float inv = 1.0f / 1.69f;   // 1/(4*sigma^2)
    size_t ob = ((size_t)(b << 16) + ((x0 + tx) << 8) + (y0 + ty0)) * 3 + c;
    out[ob]     = a0 * inv;
    out[ob + 3] = a1 * inv;
    out[ob + 6] = a2 * inv;
    out[ob + 9] = a3 * inv;
}

extern "C" void kernel_launch(void* const* d_in, const int* in_sizes, int n_in,
                              void* d_out, int out_size, void* d_ws, size_t ws_size,
                              hipStream_t stream) {
    const float* A  = (const float*)d_in[0];
    const float* Kn = (const float*)d_in[1];
    const float* m  = (const float*)d_in[2];
    const float* s  = (const float*)d_in[3];
    const float* h  = (const float*)d_in[4];

    char* ws = (char*)d_ws;
    int*          radii = (int*)ws;                        // 16 B
    int*          nschd = (int*)(ws + 16);
    int*          rowr  = (int*)(ws + 64);                 // 267*4
    int2*         meta  = (int2*)(ws + 2048);              // 267*8
    int2*         meta2 = (int2*)(ws + 8192);              // 267*8
    unsigned int* sched = (unsigned int*)(ws + 16384);     // 12 KB
    f16*          Atr   = (f16*)(ws + 32768);              // 1.57 MB
    uint4*        bpack = (uint4*)(ws + 1605632);          // 2.19 MB
    f16*          Uc    = (f16*)(ws + 3793920);            // 1.57 MB -> ends 5.37 MB

    lenia_meta<<<3 * NROWS, 128, 0, stream>>>(Kn, meta, rowr);
    lenia_sched<<<3, 128, 0, stream>>>(meta, rowr, meta2, sched, nschd, radii);
    lenia_prep2<<<NBPK + 1024, 256, 0, stream>>>(Kn, A, meta2, bpack, Atr);
    lenia_conv<<<dim3(64, 12), 512, TROWS * ST * sizeof(f16), stream>>>(
        Atr, bpack, sched, nschd, radii, m, s, h, Uc);
    lenia_flowrt<<<dim3(64, 12), 256, 8 * PLH + PLH * 8, stream>>>(
        Atr, Uc, (float*)d_out);
}